// Round 1
// baseline (1230.698 us; speedup 1.0000x reference)
//
#include <hip/hip_runtime.h>

#define N_NODES 50000
#define N_EDGES 600000
#define H 128

typedef __bf16 bf16x8 __attribute__((ext_vector_type(8)));
typedef float f32x4 __attribute__((ext_vector_type(4)));
typedef unsigned short u16;
typedef u16 u16x8 __attribute__((ext_vector_type(8)));

// bf16 weight layout offsets (elements) in d_ws, all transposed to [128][K]
#define WT_E1 0
#define WT_E2 49152
#define WT_E3 65536
#define WT_E4 81920
#define WT_N1 98304
#define WT_N2 131072
#define WT_N3 147456
#define WT_N4 163840
#define WT_TOTAL 180224
#define AGG_BYTE_OFF (WT_TOTAL * 2)

__device__ inline u16 f2bf(float f) {
  return __builtin_bit_cast(u16, (__bf16)f);
}

__global__ __launch_bounds__(256) void prep_weights(
    const float* __restrict__ ew1, const float* __restrict__ ew2,
    const float* __restrict__ ew3, const float* __restrict__ ew4,
    const float* __restrict__ nw1, const float* __restrict__ nw2,
    const float* __restrict__ nw3, const float* __restrict__ nw4,
    u16* __restrict__ wt)
{
  const int gid = blockIdx.x * 256 + threadIdx.x;
  int base, K; const float* src;
  if      (gid < 49152)  { base = WT_E1; K = 384; src = ew1; }
  else if (gid < 65536)  { base = WT_E2; K = 128; src = ew2; }
  else if (gid < 81920)  { base = WT_E3; K = 128; src = ew3; }
  else if (gid < 98304)  { base = WT_E4; K = 128; src = ew4; }
  else if (gid < 131072) { base = WT_N1; K = 256; src = nw1; }
  else if (gid < 147456) { base = WT_N2; K = 128; src = nw2; }
  else if (gid < 163840) { base = WT_N3; K = 128; src = nw3; }
  else if (gid < 180224) { base = WT_N4; K = 128; src = nw4; }
  else return;
  const int idx = gid - base;
  const int n = idx / K, k = idx - n * K;
  wt[gid] = f2bf(src[k * H + n]);   // transpose: wt[n][k] = w[k][n]
}

// One MLP layer: acc[n] (8 col-tiles of 16x16) = A(16 rows of this wave, K) @ W(K,128)
// A in LDS bf16, XOR-swizzled; W in global bf16 transposed [128][K].
// mfma_f32_16x16x32_bf16 layouts (HW-verified per guide):
//   A: row = lane&15, k = (lane>>4)*8 + j (contiguous 8)
//   B: col = lane&15, k = (lane>>4)*8 + j
//   D: col = lane&15, row = (lane>>4)*4 + reg
template<int K>
__device__ inline void run_layer(const u16* sA, const int pitchB,
                                 const u16* __restrict__ wt,
                                 const int lane, const int w, f32x4 acc[8])
{
  const int rowA = (w << 4) + (lane & 15);
  const int kg = lane >> 4;
  const int swz = (rowA & 7) << 4;
  const char* aRow = (const char*)sA + rowA * pitchB;
  const int col16 = lane & 15;
#pragma unroll
  for (int n = 0; n < 8; ++n) acc[n] = {0.f, 0.f, 0.f, 0.f};
#pragma unroll 2
  for (int k0 = 0; k0 < K; k0 += 32) {
    const int kb = (k0 + kg * 8) * 2;
    const u16x8 av = *(const u16x8*)(aRow + (kb ^ swz));
    const bf16x8 a = __builtin_bit_cast(bf16x8, av);
#pragma unroll
    for (int n = 0; n < 8; ++n) {
      const u16x8 bv = *(const u16x8*)(wt + (n * 16 + col16) * K + k0 + kg * 8);
      acc[n] = __builtin_amdgcn_mfma_f32_16x16x32_bf16(
          a, __builtin_bit_cast(bf16x8, bv), acc[n], 0, 0, 0);
    }
  }
}

// bias + relu + bf16 -> swizzled LDS h tile [64][128]
__device__ inline void store_h(u16* sH, const f32x4 acc[8],
                               const float* __restrict__ bias,
                               const int lane, const int w)
{
  const int kg = lane >> 4;
  const int col16 = lane & 15;
#pragma unroll
  for (int n = 0; n < 8; ++n) {
    const int col = n * 16 + col16;
    const float bb = bias[col];
#pragma unroll
    for (int r = 0; r < 4; ++r) {
      const int row = (w << 4) + kg * 4 + r;
      float v = acc[n][r] + bb;
      v = v > 0.f ? v : 0.f;
      *(u16*)((char*)sH + row * 256 + ((col * 2) ^ ((row & 7) << 4))) = f2bf(v);
    }
  }
}

__global__ __launch_bounds__(256) void edge_kernel(
    const float* __restrict__ x, const float* __restrict__ ea,
    const int* __restrict__ eidx, const u16* __restrict__ wt,
    const float* __restrict__ b1, const float* __restrict__ b2,
    const float* __restrict__ b3, const float* __restrict__ b4,
    const float* __restrict__ g, const float* __restrict__ be,
    float* __restrict__ out2, float* __restrict__ agg)
{
  __shared__ u16 sIn[64 * 384];   // 48 KiB; h tiles ping-pong inside after L1
  const int e0 = blockIdx.x * 64;
  const int tid = threadIdx.x;
  const int lane = tid & 63, w = tid >> 6;
  const int* __restrict__ snd = eidx;
  const int* __restrict__ rcv = eidx + N_EDGES;

  // stage concat(x[snd], x[rcv], ea) as bf16 into swizzled LDS [64][384]
  for (int i = tid; i < 64 * 48; i += 256) {
    const int r = i / 48, c = i - r * 48;
    const int e = e0 + r;
    const float* src; int cc;
    if (c < 16)      { src = x + (size_t)snd[e] * H; cc = c; }
    else if (c < 32) { src = x + (size_t)rcv[e] * H; cc = c - 16; }
    else             { src = ea + (size_t)e * H;     cc = c - 32; }
    const float4 f0 = ((const float4*)src)[cc * 2];
    const float4 f1 = ((const float4*)src)[cc * 2 + 1];
    u16x8 o;
    o[0] = f2bf(f0.x); o[1] = f2bf(f0.y); o[2] = f2bf(f0.z); o[3] = f2bf(f0.w);
    o[4] = f2bf(f1.x); o[5] = f2bf(f1.y); o[6] = f2bf(f1.z); o[7] = f2bf(f1.w);
    *(u16x8*)((char*)sIn + r * 768 + ((c * 16) ^ ((r & 7) << 4))) = o;
  }
  __syncthreads();

  f32x4 acc[8];
  run_layer<384>(sIn, 768, wt + WT_E1, lane, w, acc);
  __syncthreads();
  store_h(sIn, acc, b1, lane, w);
  __syncthreads();
  run_layer<128>(sIn, 256, wt + WT_E2, lane, w, acc);
  __syncthreads();
  store_h(sIn + 64 * 128, acc, b2, lane, w);
  __syncthreads();
  run_layer<128>(sIn + 64 * 128, 256, wt + WT_E3, lane, w, acc);
  __syncthreads();
  store_h(sIn, acc, b3, lane, w);
  __syncthreads();
  run_layer<128>(sIn, 256, wt + WT_E4, lane, w, acc);

  // bias4 + LayerNorm + residual write + scatter-add
  const int kg = lane >> 4;
  const int col16 = lane & 15;
  float val[8][4];
  float vs[4] = {0, 0, 0, 0}, vq[4] = {0, 0, 0, 0};
#pragma unroll
  for (int n = 0; n < 8; ++n) {
    const float bb = b4[n * 16 + col16];
#pragma unroll
    for (int r = 0; r < 4; ++r) {
      const float v = acc[n][r] + bb;
      val[n][r] = v; vs[r] += v; vq[r] += v * v;
    }
  }
#pragma unroll
  for (int d = 1; d < 16; d <<= 1) {
#pragma unroll
    for (int r = 0; r < 4; ++r) {
      vs[r] += __shfl_xor(vs[r], d, 64);
      vq[r] += __shfl_xor(vq[r], d, 64);
    }
  }
#pragma unroll
  for (int r = 0; r < 4; ++r) {
    const float mean = vs[r] * (1.0f / 128.0f);
    const float var = vq[r] * (1.0f / 128.0f) - mean * mean;
    const float rstd = rsqrtf(var + 1e-5f);
    const int rowg = e0 + (w << 4) + kg * 4 + r;
    const int rv = rcv[rowg];
    const size_t rbase = (size_t)rowg * H;
    const size_t abase = (size_t)rv * H;
#pragma unroll
    for (int n = 0; n < 8; ++n) {
      const int col = n * 16 + col16;
      const float ne = (val[n][r] - mean) * rstd * g[col] + be[col];
      out2[rbase + col] = ea[rbase + col] + ne;
      atomicAdd(agg + abase + col, ne);
    }
  }
}

__global__ __launch_bounds__(256) void node_kernel(
    const float* __restrict__ x, const float* __restrict__ agg,
    const u16* __restrict__ wt,
    const float* __restrict__ b1, const float* __restrict__ b2,
    const float* __restrict__ b3, const float* __restrict__ b4,
    const float* __restrict__ g, const float* __restrict__ be,
    float* __restrict__ out1)
{
  __shared__ u16 sIn[64 * 256];   // 32 KiB
  const int n0 = blockIdx.x * 64;
  const int tid = threadIdx.x;
  const int lane = tid & 63, w = tid >> 6;

  for (int i = tid; i < 64 * 32; i += 256) {
    const int r = i >> 5, c = i & 31;
    const int node = n0 + r;
    u16x8 o;
    if (node < N_NODES) {
      const float* src = (c < 16) ? (x + (size_t)node * H) : (agg + (size_t)node * H);
      const int cc = c & 15;
      const float4 f0 = ((const float4*)src)[cc * 2];
      const float4 f1 = ((const float4*)src)[cc * 2 + 1];
      o[0] = f2bf(f0.x); o[1] = f2bf(f0.y); o[2] = f2bf(f0.z); o[3] = f2bf(f0.w);
      o[4] = f2bf(f1.x); o[5] = f2bf(f1.y); o[6] = f2bf(f1.z); o[7] = f2bf(f1.w);
    } else {
#pragma unroll
      for (int j = 0; j < 8; ++j) o[j] = 0;
    }
    *(u16x8*)((char*)sIn + r * 512 + ((c * 16) ^ ((r & 7) << 4))) = o;
  }
  __syncthreads();

  f32x4 acc[8];
  run_layer<256>(sIn, 512, wt + WT_N1, lane, w, acc);
  __syncthreads();
  store_h(sIn, acc, b1, lane, w);
  __syncthreads();
  run_layer<128>(sIn, 256, wt + WT_N2, lane, w, acc);
  __syncthreads();
  store_h(sIn + 64 * 128, acc, b2, lane, w);
  __syncthreads();
  run_layer<128>(sIn + 64 * 128, 256, wt + WT_N3, lane, w, acc);
  __syncthreads();
  store_h(sIn, acc, b3, lane, w);
  __syncthreads();
  run_layer<128>(sIn, 256, wt + WT_N4, lane, w, acc);

  const int kg = lane >> 4;
  const int col16 = lane & 15;
  float val[8][4];
  float vs[4] = {0, 0, 0, 0}, vq[4] = {0, 0, 0, 0};
#pragma unroll
  for (int n = 0; n < 8; ++n) {
    const float bb = b4[n * 16 + col16];
#pragma unroll
    for (int r = 0; r < 4; ++r) {
      const float v = acc[n][r] + bb;
      val[n][r] = v; vs[r] += v; vq[r] += v * v;
    }
  }
#pragma unroll
  for (int d = 1; d < 16; d <<= 1) {
#pragma unroll
    for (int r = 0; r < 4; ++r) {
      vs[r] += __shfl_xor(vs[r], d, 64);
      vq[r] += __shfl_xor(vq[r], d, 64);
    }
  }
#pragma unroll
  for (int r = 0; r < 4; ++r) {
    const float mean = vs[r] * (1.0f / 128.0f);
    const float var = vq[r] * (1.0f / 128.0f) - mean * mean;
    const float rstd = rsqrtf(var + 1e-5f);
    const int rowg = n0 + (w << 4) + kg * 4 + r;
    if (rowg < N_NODES) {
      const size_t rbase = (size_t)rowg * H;
#pragma unroll
      for (int n = 0; n < 8; ++n) {
        const int col = n * 16 + col16;
        const float ne = (val[n][r] - mean) * rstd * g[col] + be[col];
        out1[rbase + col] = x[rbase + col] + ne;
      }
    }
  }
}

extern "C" void kernel_launch(void* const* d_in, const int* in_sizes, int n_in,
                              void* d_out, int out_size, void* d_ws, size_t ws_size,
                              hipStream_t stream) {
  const float* x   = (const float*)d_in[0];
  const float* ea  = (const float*)d_in[1];
  const int*   ei  = (const int*)d_in[2];
  const float* ew1 = (const float*)d_in[3];
  const float* eb1 = (const float*)d_in[4];
  const float* ew2 = (const float*)d_in[5];
  const float* eb2 = (const float*)d_in[6];
  const float* ew3 = (const float*)d_in[7];
  const float* eb3 = (const float*)d_in[8];
  const float* ew4 = (const float*)d_in[9];
  const float* eb4 = (const float*)d_in[10];
  const float* eg  = (const float*)d_in[11];
  const float* ebe = (const float*)d_in[12];
  const float* nw1 = (const float*)d_in[13];
  const float* nb1 = (const float*)d_in[14];
  const float* nw2 = (const float*)d_in[15];
  const float* nb2 = (const float*)d_in[16];
  const float* nw3 = (const float*)d_in[17];
  const float* nb3 = (const float*)d_in[18];
  const float* nw4 = (const float*)d_in[19];
  const float* nb4 = (const float*)d_in[20];
  const float* ng  = (const float*)d_in[21];
  const float* nbe = (const float*)d_in[22];

  u16* wt = (u16*)d_ws;
  float* agg = (float*)((char*)d_ws + AGG_BYTE_OFF);
  float* out1 = (float*)d_out;
  float* out2 = out1 + (size_t)N_NODES * H;

  hipMemsetAsync(agg, 0, (size_t)N_NODES * H * sizeof(float), stream);
  prep_weights<<<WT_TOTAL / 256, 256, 0, stream>>>(ew1, ew2, ew3, ew4,
                                                   nw1, nw2, nw3, nw4, wt);
  edge_kernel<<<N_EDGES / 64, 256, 0, stream>>>(x, ea, ei, wt,
                                                eb1, eb2, eb3, eb4, eg, ebe,
                                                out2, agg);
  node_kernel<<<(N_NODES + 63) / 64, 256, 0, stream>>>(x, agg, wt,
                                                       nb1, nb2, nb3, nb4, ng, nbe,
                                                       out1);
}

// Round 2
// 1117.890 us; speedup vs baseline: 1.1009x; 1.1009x over previous
//
#include <hip/hip_runtime.h>

#define N_NODES 50000
#define N_EDGES 600000
#define H 128

typedef __bf16 bf16x8 __attribute__((ext_vector_type(8)));
typedef float f32x4 __attribute__((ext_vector_type(4)));
typedef unsigned short u16;
typedef u16 u16x8 __attribute__((ext_vector_type(8)));

// bf16 weight layout offsets (elements) in d_ws, all transposed to [128][K]
#define WT_E1 0
#define WT_E2 49152
#define WT_E3 65536
#define WT_E4 81920
#define WT_N1 98304
#define WT_N2 131072
#define WT_N3 147456
#define WT_N4 163840
#define WT_TOTAL 180224
#define AGG_BYTE_OFF (WT_TOTAL * 2)

__device__ inline u16 f2bf(float f) {
  return __builtin_bit_cast(u16, (__bf16)f);
}

// load 8 consecutive f32, convert to packed bf16x8 (as u16x8)
__device__ inline u16x8 cvt8(const float* __restrict__ p) {
  const float4 f0 = ((const float4*)p)[0];
  const float4 f1 = ((const float4*)p)[1];
  u16x8 o;
  o[0] = f2bf(f0.x); o[1] = f2bf(f0.y); o[2] = f2bf(f0.z); o[3] = f2bf(f0.w);
  o[4] = f2bf(f1.x); o[5] = f2bf(f1.y); o[6] = f2bf(f1.z); o[7] = f2bf(f1.w);
  return o;
}

__global__ __launch_bounds__(256) void prep_weights(
    const float* __restrict__ ew1, const float* __restrict__ ew2,
    const float* __restrict__ ew3, const float* __restrict__ ew4,
    const float* __restrict__ nw1, const float* __restrict__ nw2,
    const float* __restrict__ nw3, const float* __restrict__ nw4,
    u16* __restrict__ wt)
{
  const int gid = blockIdx.x * 256 + threadIdx.x;
  int base, K; const float* src;
  if      (gid < 49152)  { base = WT_E1; K = 384; src = ew1; }
  else if (gid < 65536)  { base = WT_E2; K = 128; src = ew2; }
  else if (gid < 81920)  { base = WT_E3; K = 128; src = ew3; }
  else if (gid < 98304)  { base = WT_E4; K = 128; src = ew4; }
  else if (gid < 131072) { base = WT_N1; K = 256; src = nw1; }
  else if (gid < 147456) { base = WT_N2; K = 128; src = nw2; }
  else if (gid < 163840) { base = WT_N3; K = 128; src = nw3; }
  else if (gid < 180224) { base = WT_N4; K = 128; src = nw4; }
  else return;
  const int idx = gid - base;
  const int n = idx / K, k = idx - n * K;
  wt[gid] = f2bf(src[k * H + n]);   // transpose: wt[n][k] = w[k][n]
}

// mfma_f32_16x16x32_bf16 layouts (HW-verified in R1, absmax 0.031):
//   A: row = lane&15, k = (lane>>4)*8 + j (contiguous 8)
//   B: col = lane&15, k = (lane>>4)*8 + j
//   D: col = lane&15, row = (lane>>4)*4 + reg

// Layer with A in registers (NC chunks of k-32). W transposed [128][NC*32].
template<int NC>
__device__ inline void layer_reg(const u16x8 aReg[NC],
                                 const u16* __restrict__ wt,
                                 const int col16, const int kg, f32x4 acc[8])
{
#pragma unroll
  for (int n = 0; n < 8; ++n) acc[n] = {0.f, 0.f, 0.f, 0.f};
#pragma unroll
  for (int k0 = 0; k0 < NC; ++k0) {
    const bf16x8 a = __builtin_bit_cast(bf16x8, aReg[k0]);
#pragma unroll
    for (int n = 0; n < 8; ++n) {
      const u16x8 bv = *(const u16x8*)(wt + (n * 16 + col16) * (NC * 32) + k0 * 32 + kg * 8);
      acc[n] = __builtin_amdgcn_mfma_f32_16x16x32_bf16(
          a, __builtin_bit_cast(bf16x8, bv), acc[n], 0, 0, 0);
    }
  }
}

// Layer with A in per-wave LDS tile [16][128] bf16, XOR-swizzled, pitch 256B. K=128.
__device__ inline void layer_lds(const u16* tile, const u16* __restrict__ wt,
                                 const int la, const int kg, const int col16,
                                 f32x4 acc[8])
{
  const int swz = (la & 7) << 4;
  const char* aRow = (const char*)tile + la * 256;
#pragma unroll
  for (int n = 0; n < 8; ++n) acc[n] = {0.f, 0.f, 0.f, 0.f};
#pragma unroll
  for (int k0 = 0; k0 < 4; ++k0) {
    const u16x8 av = *(const u16x8*)(aRow + ((k0 * 64 + kg * 16) ^ swz));
    const bf16x8 a = __builtin_bit_cast(bf16x8, av);
#pragma unroll
    for (int n = 0; n < 8; ++n) {
      const u16x8 bv = *(const u16x8*)(wt + (n * 16 + col16) * 128 + k0 * 32 + kg * 8);
      acc[n] = __builtin_amdgcn_mfma_f32_16x16x32_bf16(
          a, __builtin_bit_cast(bf16x8, bv), acc[n], 0, 0, 0);
    }
  }
}

// bias + relu + bf16 -> per-wave swizzled LDS tile [16][128]
__device__ inline void store_tile(u16* tile, const f32x4 acc[8],
                                  const float* __restrict__ bias,
                                  const int kg, const int col16)
{
#pragma unroll
  for (int n = 0; n < 8; ++n) {
    const int col = n * 16 + col16;
    const float bb = bias[col];
#pragma unroll
    for (int r = 0; r < 4; ++r) {
      const int lr = kg * 4 + r;
      float v = acc[n][r] + bb;
      v = v > 0.f ? v : 0.f;
      *(u16*)((char*)tile + lr * 256 + ((col * 2) ^ ((lr & 7) << 4))) = f2bf(v);
    }
  }
}

__global__ __launch_bounds__(256) void edge_kernel(
    const float* __restrict__ x, const float* __restrict__ ea,
    const int* __restrict__ eidx, const u16* __restrict__ wt,
    const float* __restrict__ b1, const float* __restrict__ b2,
    const float* __restrict__ b3, const float* __restrict__ b4,
    const float* __restrict__ g, const float* __restrict__ be,
    float* __restrict__ out2, float* __restrict__ agg)
{
  __shared__ u16 sH[4][2048];   // per-wave [16][128] bf16 tile, 16 KiB total
  const int tid = threadIdx.x;
  const int lane = tid & 63, w = tid >> 6;
  const int e0 = blockIdx.x * 64 + w * 16;   // this wave's 16 edges
  const int la = lane & 15;                  // A-row / D-col index
  const int kg = lane >> 4;
  const int* __restrict__ snd = eidx;
  const int* __restrict__ rcv = eidx + N_EDGES;

  // ---- gather L1 input directly into registers (no LDS, no barrier) ----
  const int myRow = e0 + la;
  const int sN = snd[myRow], rN = rcv[myRow];
  const float* px = x + (size_t)sN * H + kg * 8;
  const float* pr = x + (size_t)rN * H + kg * 8;
  const float* pe = ea + (size_t)myRow * H + kg * 8;
  u16x8 aReg[12];
#pragma unroll
  for (int c = 0; c < 4; ++c) aReg[c] = cvt8(px + c * 32);
#pragma unroll
  for (int c = 0; c < 4; ++c) aReg[4 + c] = cvt8(pr + c * 32);
#pragma unroll
  for (int c = 0; c < 4; ++c) aReg[8 + c] = cvt8(pe + c * 32);

  f32x4 acc[8];
  u16* tile = sH[w];
  layer_reg<12>(aReg, wt + WT_E1, la, kg, acc);
  store_tile(tile, acc, b1, kg, la);
  layer_lds(tile, wt + WT_E2, la, kg, la, acc);
  store_tile(tile, acc, b2, kg, la);
  layer_lds(tile, wt + WT_E3, la, kg, la, acc);
  store_tile(tile, acc, b3, kg, la);
  layer_lds(tile, wt + WT_E4, la, kg, la, acc);

  // ---- bias4 + LayerNorm + residual write + scatter-add ----
  float val[8][4];
  float vs[4] = {0, 0, 0, 0}, vq[4] = {0, 0, 0, 0};
#pragma unroll
  for (int n = 0; n < 8; ++n) {
    const float bb = b4[n * 16 + la];
#pragma unroll
    for (int r = 0; r < 4; ++r) {
      const float v = acc[n][r] + bb;
      val[n][r] = v; vs[r] += v; vq[r] += v * v;
    }
  }
#pragma unroll
  for (int d = 1; d < 16; d <<= 1) {
#pragma unroll
    for (int r = 0; r < 4; ++r) {
      vs[r] += __shfl_xor(vs[r], d, 64);
      vq[r] += __shfl_xor(vq[r], d, 64);
    }
  }
#pragma unroll
  for (int r = 0; r < 4; ++r) {
    const float mean = vs[r] * (1.0f / 128.0f);
    const float var = vq[r] * (1.0f / 128.0f) - mean * mean;
    const float rstd = rsqrtf(var + 1e-5f);
    const int rowg = e0 + kg * 4 + r;
    const int rv = rcv[rowg];
    const size_t rbase = (size_t)rowg * H;
    const size_t abase = (size_t)rv * H;
#pragma unroll
    for (int n = 0; n < 8; ++n) {
      const int col = n * 16 + la;
      const float ne = (val[n][r] - mean) * rstd * g[col] + be[col];
      out2[rbase + col] = ea[rbase + col] + ne;
      atomicAdd(agg + abase + col, ne);
    }
  }
}

__global__ __launch_bounds__(256) void node_kernel(
    const float* __restrict__ x, const float* __restrict__ agg,
    const u16* __restrict__ wt,
    const float* __restrict__ b1, const float* __restrict__ b2,
    const float* __restrict__ b3, const float* __restrict__ b4,
    const float* __restrict__ g, const float* __restrict__ be,
    float* __restrict__ out1)
{
  __shared__ u16 sH[4][2048];
  const int tid = threadIdx.x;
  const int lane = tid & 63, w = tid >> 6;
  const int n0 = blockIdx.x * 64 + w * 16;
  const int la = lane & 15;
  const int kg = lane >> 4;

  const int myRow = n0 + la;
  const int cr = myRow < N_NODES ? myRow : N_NODES - 1;   // clamp; rows independent in MFMA
  const float* px = x   + (size_t)cr * H + kg * 8;
  const float* pa = agg + (size_t)cr * H + kg * 8;
  u16x8 aReg[8];
#pragma unroll
  for (int c = 0; c < 4; ++c) aReg[c] = cvt8(px + c * 32);
#pragma unroll
  for (int c = 0; c < 4; ++c) aReg[4 + c] = cvt8(pa + c * 32);

  f32x4 acc[8];
  u16* tile = sH[w];
  layer_reg<8>(aReg, wt + WT_N1, la, kg, acc);
  store_tile(tile, acc, b1, kg, la);
  layer_lds(tile, wt + WT_N2, la, kg, la, acc);
  store_tile(tile, acc, b2, kg, la);
  layer_lds(tile, wt + WT_N3, la, kg, la, acc);
  store_tile(tile, acc, b3, kg, la);
  layer_lds(tile, wt + WT_N4, la, kg, la, acc);

  float val[8][4];
  float vs[4] = {0, 0, 0, 0}, vq[4] = {0, 0, 0, 0};
#pragma unroll
  for (int n = 0; n < 8; ++n) {
    const float bb = b4[n * 16 + la];
#pragma unroll
    for (int r = 0; r < 4; ++r) {
      const float v = acc[n][r] + bb;
      val[n][r] = v; vs[r] += v; vq[r] += v * v;
    }
  }
#pragma unroll
  for (int d = 1; d < 16; d <<= 1) {
#pragma unroll
    for (int r = 0; r < 4; ++r) {
      vs[r] += __shfl_xor(vs[r], d, 64);
      vq[r] += __shfl_xor(vq[r], d, 64);
    }
  }
#pragma unroll
  for (int r = 0; r < 4; ++r) {
    const float mean = vs[r] * (1.0f / 128.0f);
    const float var = vq[r] * (1.0f / 128.0f) - mean * mean;
    const float rstd = rsqrtf(var + 1e-5f);
    const int rowg = n0 + kg * 4 + r;
    if (rowg < N_NODES) {
      const size_t rbase = (size_t)rowg * H;
#pragma unroll
      for (int n = 0; n < 8; ++n) {
        const int col = n * 16 + la;
        const float ne = (val[n][r] - mean) * rstd * g[col] + be[col];
        out1[rbase + col] = x[rbase + col] + ne;
      }
    }
  }
}

extern "C" void kernel_launch(void* const* d_in, const int* in_sizes, int n_in,
                              void* d_out, int out_size, void* d_ws, size_t ws_size,
                              hipStream_t stream) {
  const float* x   = (const float*)d_in[0];
  const float* ea  = (const float*)d_in[1];
  const int*   ei  = (const int*)d_in[2];
  const float* ew1 = (const float*)d_in[3];
  const float* eb1 = (const float*)d_in[4];
  const float* ew2 = (const float*)d_in[5];
  const float* eb2 = (const float*)d_in[6];
  const float* ew3 = (const float*)d_in[7];
  const float* eb3 = (const float*)d_in[8];
  const float* ew4 = (const float*)d_in[9];
  const float* eb4 = (const float*)d_in[10];
  const float* eg  = (const float*)d_in[11];
  const float* ebe = (const float*)d_in[12];
  const float* nw1 = (const float*)d_in[13];
  const float* nb1 = (const float*)d_in[14];
  const float* nw2 = (const float*)d_in[15];
  const float* nb2 = (const float*)d_in[16];
  const float* nw3 = (const float*)d_in[17];
  const float* nb3 = (const float*)d_in[18];
  const float* nw4 = (const float*)d_in[19];
  const float* nb4 = (const float*)d_in[20];
  const float* ng  = (const float*)d_in[21];
  const float* nbe = (const float*)d_in[22];

  u16* wt = (u16*)d_ws;
  float* agg = (float*)((char*)d_ws + AGG_BYTE_OFF);
  float* out1 = (float*)d_out;
  float* out2 = out1 + (size_t)N_NODES * H;

  hipMemsetAsync(agg, 0, (size_t)N_NODES * H * sizeof(float), stream);
  prep_weights<<<WT_TOTAL / 256, 256, 0, stream>>>(ew1, ew2, ew3, ew4,
                                                   nw1, nw2, nw3, nw4, wt);
  edge_kernel<<<N_EDGES / 64, 256, 0, stream>>>(x, ea, ei, wt,
                                                eb1, eb2, eb3, eb4, eg, ebe,
                                                out2, agg);
  node_kernel<<<(N_NODES + 63) / 64, 256, 0, stream>>>(x, agg, wt,
                                                       nb1, nb2, nb3, nb4, ng, nbe,
                                                       out1);
}

// Round 3
// 1083.223 us; speedup vs baseline: 1.1361x; 1.0320x over previous
//
#include <hip/hip_runtime.h>

#define N_NODES 50000
#define N_EDGES 600000
#define H 128

typedef __bf16 bf16x8 __attribute__((ext_vector_type(8)));
typedef float f32x4 __attribute__((ext_vector_type(4)));
typedef unsigned short u16;
typedef u16 u16x8 __attribute__((ext_vector_type(8)));

// d_ws layout (bytes):
//   wt: 11 matrices, each [128][128] bf16 transposed ([n][k], wt[n][k]=W[k][n])
//     0:E_W1a 1:E_W1b 2:E_W1c 3:E_W2 4:E_W3 5:E_W4 6:N_W1a 7:N_W1b 8:N_W2 9:N_W3 10:N_W4
#define MW 16384
#define WT_BYTES (11 * MW * 2)                     // 360448
#define XA_OFF WT_BYTES                            // 50000*128 bf16
#define XB_OFF (XA_OFF + N_NODES * H * 2)
#define XN_OFF (XB_OFF + N_NODES * H * 2)
#define AGG_OFF (XN_OFF + N_NODES * H * 2)         // f32

__device__ inline u16 f2bf(float f) { return __builtin_bit_cast(u16, (__bf16)f); }
__device__ inline float bf2f(u16 u) {
  unsigned v = (unsigned)u << 16;
  return __builtin_bit_cast(float, v);
}

__device__ inline u16x8 cvt8(const float* __restrict__ p) {
  const float4 f0 = ((const float4*)p)[0];
  const float4 f1 = ((const float4*)p)[1];
  u16x8 o;
  o[0] = f2bf(f0.x); o[1] = f2bf(f0.y); o[2] = f2bf(f0.z); o[3] = f2bf(f0.w);
  o[4] = f2bf(f1.x); o[5] = f2bf(f1.y); o[6] = f2bf(f1.z); o[7] = f2bf(f1.w);
  return o;
}

__global__ __launch_bounds__(256) void prep_weights(
    const float* __restrict__ ew1, const float* __restrict__ ew2,
    const float* __restrict__ ew3, const float* __restrict__ ew4,
    const float* __restrict__ nw1, const float* __restrict__ nw2,
    const float* __restrict__ nw3, const float* __restrict__ nw4,
    u16* __restrict__ wt)
{
  const int gid = blockIdx.x * 256 + threadIdx.x;
  if (gid >= 11 * MW) return;
  const int mat = gid >> 14, idx = gid & (MW - 1);
  const int n = idx >> 7, k = idx & 127;
  const float* src; int ro = 0;
  switch (mat) {
    case 0: src = ew1; ro = 0;   break;
    case 1: src = ew1; ro = 128; break;
    case 2: src = ew1; ro = 256; break;
    case 3: src = ew2; break;
    case 4: src = ew3; break;
    case 5: src = ew4; break;
    case 6: src = nw1; ro = 0;   break;
    case 7: src = nw1; ro = 128; break;
    case 8: src = nw2; break;
    case 9: src = nw3; break;
    default: src = nw4; break;
  }
  wt[gid] = f2bf(src[(ro + k) * H + n]);
}

// mfma_f32_16x16x32_bf16 layouts (HW-verified R1, absmax 0.031):
//   A: row = lane&15, k = (lane>>4)*8 + j
//   B: col = lane&15, k = (lane>>4)*8 + j
//   D: col = lane&15, row = (lane>>4)*4 + reg

// XA = x@E_W1a, XB = x@E_W1b, XN = x@N_W1a for all nodes, stored bf16
__global__ __launch_bounds__(256) void precompute(
    const float* __restrict__ x, const u16* __restrict__ wt,
    u16* __restrict__ xa, u16* __restrict__ xb, u16* __restrict__ xn)
{
  const int tid = threadIdx.x;
  const int lane = tid & 63, w = tid >> 6;
  const int n0 = blockIdx.x * 64 + w * 16;
  const int la = lane & 15, kg = lane >> 4;
  const int row = n0 + la < N_NODES ? n0 + la : N_NODES - 1;

  u16x8 af[4];
#pragma unroll
  for (int k0 = 0; k0 < 4; ++k0)
    af[k0] = cvt8(x + (size_t)row * H + k0 * 32 + kg * 8);

  const int mats[3] = {0, 1, 6};
  u16* outs[3] = {xa, xb, xn};
#pragma unroll
  for (int m = 0; m < 3; ++m) {
    const u16* wm = wt + mats[m] * MW;
    f32x4 acc[8];
#pragma unroll
    for (int n = 0; n < 8; ++n) acc[n] = {0.f, 0.f, 0.f, 0.f};
#pragma unroll
    for (int k0 = 0; k0 < 4; ++k0) {
      const bf16x8 a = __builtin_bit_cast(bf16x8, af[k0]);
#pragma unroll
      for (int n = 0; n < 8; ++n) {
        const u16x8 bv = *(const u16x8*)(wm + (n * 16 + la) * 128 + k0 * 32 + kg * 8);
        acc[n] = __builtin_amdgcn_mfma_f32_16x16x32_bf16(
            a, __builtin_bit_cast(bf16x8, bv), acc[n], 0, 0, 0);
      }
    }
    u16* out = outs[m];
#pragma unroll
    for (int r = 0; r < 4; ++r) {
      const int rg = n0 + kg * 4 + r;
      if (rg < N_NODES) {
#pragma unroll
        for (int n = 0; n < 8; ++n)
          out[(size_t)rg * H + n * 16 + la] = f2bf(acc[n][r]);
      }
    }
  }
}

__global__ __launch_bounds__(256) void edge_kernel(
    const float* __restrict__ ea, const int* __restrict__ eidx,
    const u16* __restrict__ wt,
    const u16* __restrict__ xag, const u16* __restrict__ xbg,
    const float* __restrict__ b1, const float* __restrict__ b2,
    const float* __restrict__ b3, const float* __restrict__ b4,
    const float* __restrict__ g, const float* __restrict__ be,
    float* __restrict__ out2, float* __restrict__ agg)
{
  __shared__ u16 sH[4][4096];   // per-wave [32][128] bf16 tile (8 KiB), 32 KiB block
  const int tid = threadIdx.x;
  const int lane = tid & 63, w = tid >> 6;
  const int e0 = blockIdx.x * 128 + w * 32;   // this wave's 32 edges
  const int la = lane & 15, kg = lane >> 4;
  const int* __restrict__ snd = eidx;
  const int* __restrict__ rcv = eidx + N_EDGES;
  u16* tile = sH[w];
  char* tileB = (char*)tile;
  const int swzA = (la & 7) << 4;

  // rows this lane feeds as A-row (tile t: row e0+t*16+la)
  int rA[2];
  rA[0] = e0 + la;      if (rA[0] >= N_EDGES) rA[0] = N_EDGES - 1;
  rA[1] = e0 + 16 + la; if (rA[1] >= N_EDGES) rA[1] = N_EDGES - 1;

  // early: gather XA[snd], XB[rcv] bf16 A-fragments (longest-latency loads)
  u16x8 xa[2][4], xb[2][4];
#pragma unroll
  for (int t = 0; t < 2; ++t) {
    const size_t sb = (size_t)snd[rA[t]] * H;
    const size_t rb = (size_t)rcv[rA[t]] * H;
#pragma unroll
    for (int k0 = 0; k0 < 4; ++k0) {
      xa[t][k0] = *(const u16x8*)(xag + sb + k0 * 32 + kg * 8);
      xb[t][k0] = *(const u16x8*)(xbg + rb + k0 * 32 + kg * 8);
    }
  }

  // ea A-fragments (f32 -> bf16)
  u16x8 af[2][4];
#pragma unroll
  for (int t = 0; t < 2; ++t)
#pragma unroll
    for (int k0 = 0; k0 < 4; ++k0)
      af[t][k0] = cvt8(ea + (size_t)rA[t] * H + k0 * 32 + kg * 8);

  // ---- L1c: S = ea @ W1c (B shared across both tiles) ----
  f32x4 acc[2][8];
#pragma unroll
  for (int t = 0; t < 2; ++t)
#pragma unroll
    for (int n = 0; n < 8; ++n) acc[t][n] = {0.f, 0.f, 0.f, 0.f};
  {
    const u16* wm = wt + 2 * MW;
#pragma unroll
    for (int k0 = 0; k0 < 4; ++k0) {
#pragma unroll
      for (int n = 0; n < 8; ++n) {
        const u16x8 bv = *(const u16x8*)(wm + (n * 16 + la) * 128 + k0 * 32 + kg * 8);
        acc[0][n] = __builtin_amdgcn_mfma_f32_16x16x32_bf16(
            __builtin_bit_cast(bf16x8, af[0][k0]), __builtin_bit_cast(bf16x8, bv),
            acc[0][n], 0, 0, 0);
        acc[1][n] = __builtin_amdgcn_mfma_f32_16x16x32_bf16(
            __builtin_bit_cast(bf16x8, af[1][k0]), __builtin_bit_cast(bf16x8, bv),
            acc[1][n], 0, 0, 0);
      }
    }
  }

  // store S + b1 (no relu) to LDS tile
#pragma unroll
  for (int t = 0; t < 2; ++t)
#pragma unroll
    for (int n = 0; n < 8; ++n) {
      const float bb = b1[n * 16 + la];
#pragma unroll
      for (int r = 0; r < 4; ++r) {
        const int lr = t * 16 + kg * 4 + r;
        *(u16*)(tileB + lr * 256 + (((n * 16 + la) * 2) ^ ((lr & 7) << 4))) =
            f2bf(acc[t][n][r] + bb);
      }
    }

  // h1 = relu(S + b1 + XA[snd] + XB[rcv]) in A-domain
  u16x8 hf[2][4];
#pragma unroll
  for (int t = 0; t < 2; ++t)
#pragma unroll
    for (int k0 = 0; k0 < 4; ++k0) {
      const u16x8 sv = *(const u16x8*)(tileB + (t * 16 + la) * 256 +
                                       ((k0 * 64 + kg * 16) ^ swzA));
      u16x8 o;
#pragma unroll
      for (int j = 0; j < 8; ++j) {
        float v = bf2f(sv[j]) + bf2f(xa[t][k0][j]) + bf2f(xb[t][k0][j]);
        o[j] = f2bf(v > 0.f ? v : 0.f);
      }
      hf[t][k0] = o;
    }

  // ---- layers 2..4 ----
#pragma unroll
  for (int L = 0; L < 3; ++L) {
    const u16* wm = wt + (3 + L) * MW;
    const float* bias = L == 0 ? b2 : (L == 1 ? b3 : b4);
#pragma unroll
    for (int t = 0; t < 2; ++t)
#pragma unroll
      for (int n = 0; n < 8; ++n) acc[t][n] = {0.f, 0.f, 0.f, 0.f};
#pragma unroll
    for (int k0 = 0; k0 < 4; ++k0) {
#pragma unroll
      for (int n = 0; n < 8; ++n) {
        const u16x8 bv = *(const u16x8*)(wm + (n * 16 + la) * 128 + k0 * 32 + kg * 8);
        acc[0][n] = __builtin_amdgcn_mfma_f32_16x16x32_bf16(
            __builtin_bit_cast(bf16x8, hf[0][k0]), __builtin_bit_cast(bf16x8, bv),
            acc[0][n], 0, 0, 0);
        acc[1][n] = __builtin_amdgcn_mfma_f32_16x16x32_bf16(
            __builtin_bit_cast(bf16x8, hf[1][k0]), __builtin_bit_cast(bf16x8, bv),
            acc[1][n], 0, 0, 0);
      }
    }
    if (L == 2) break;   // L4 result stays in acc for LN
    // store relu(acc + bias) and reload A-fragments
#pragma unroll
    for (int t = 0; t < 2; ++t)
#pragma unroll
      for (int n = 0; n < 8; ++n) {
        const float bb = bias[n * 16 + la];
#pragma unroll
        for (int r = 0; r < 4; ++r) {
          const int lr = t * 16 + kg * 4 + r;
          float v = acc[t][n][r] + bb;
          v = v > 0.f ? v : 0.f;
          *(u16*)(tileB + lr * 256 + (((n * 16 + la) * 2) ^ ((lr & 7) << 4))) = f2bf(v);
        }
      }
#pragma unroll
    for (int t = 0; t < 2; ++t)
#pragma unroll
      for (int k0 = 0; k0 < 4; ++k0)
        hf[t][k0] = *(const u16x8*)(tileB + (t * 16 + la) * 256 +
                                    ((k0 * 64 + kg * 16) ^ swzA));
  }

  // ---- bias4 + LayerNorm + residual + scatter-add ----
  float vs[2][4], vq[2][4];
#pragma unroll
  for (int t = 0; t < 2; ++t)
#pragma unroll
    for (int r = 0; r < 4; ++r) { vs[t][r] = 0.f; vq[t][r] = 0.f; }
#pragma unroll
  for (int t = 0; t < 2; ++t)
#pragma unroll
    for (int n = 0; n < 8; ++n) {
      const float bb = b4[n * 16 + la];
#pragma unroll
      for (int r = 0; r < 4; ++r) {
        const float v = acc[t][n][r] + bb;
        acc[t][n][r] = v;
        vs[t][r] += v; vq[t][r] += v * v;
      }
    }
#pragma unroll
  for (int d = 1; d < 16; d <<= 1)
#pragma unroll
    for (int t = 0; t < 2; ++t)
#pragma unroll
      for (int r = 0; r < 4; ++r) {
        vs[t][r] += __shfl_xor(vs[t][r], d, 64);
        vq[t][r] += __shfl_xor(vq[t][r], d, 64);
      }
#pragma unroll
  for (int t = 0; t < 2; ++t)
#pragma unroll
    for (int r = 0; r < 4; ++r) {
      const int rowg = e0 + t * 16 + kg * 4 + r;
      if (rowg < N_EDGES) {
        const float mean = vs[t][r] * (1.0f / 128.0f);
        const float var = vq[t][r] * (1.0f / 128.0f) - mean * mean;
        const float rstd = rsqrtf(var + 1e-5f);
        const int rv = rcv[rowg];
        const size_t rbase = (size_t)rowg * H;
        const size_t abase = (size_t)rv * H;
#pragma unroll
        for (int n = 0; n < 8; ++n) {
          const int col = n * 16 + la;
          const float ne = (acc[t][n][r] - mean) * rstd * g[col] + be[col];
          out2[rbase + col] = ea[rbase + col] + ne;
          atomicAdd(agg + abase + col, ne);
        }
      }
    }
}

__global__ __launch_bounds__(256) void node_kernel(
    const float* __restrict__ x, const float* __restrict__ agg,
    const u16* __restrict__ wt, const u16* __restrict__ xng,
    const float* __restrict__ b1, const float* __restrict__ b2,
    const float* __restrict__ b3, const float* __restrict__ b4,
    const float* __restrict__ g, const float* __restrict__ be,
    float* __restrict__ out1)
{
  __shared__ u16 sH[4][2048];
  const int tid = threadIdx.x;
  const int lane = tid & 63, w = tid >> 6;
  const int n0 = blockIdx.x * 64 + w * 16;
  const int la = lane & 15, kg = lane >> 4;
  u16* tile = sH[w];
  char* tileB = (char*)tile;
  const int swzA = (la & 7) << 4;

  const int row = n0 + la < N_NODES ? n0 + la : N_NODES - 1;

  u16x8 xn[4], af[4];
#pragma unroll
  for (int k0 = 0; k0 < 4; ++k0) {
    xn[k0] = *(const u16x8*)(xng + (size_t)row * H + k0 * 32 + kg * 8);
    af[k0] = cvt8(agg + (size_t)row * H + k0 * 32 + kg * 8);
  }

  // L1b: S = agg @ N_W1b
  f32x4 acc[8];
#pragma unroll
  for (int n = 0; n < 8; ++n) acc[n] = {0.f, 0.f, 0.f, 0.f};
  {
    const u16* wm = wt + 7 * MW;
#pragma unroll
    for (int k0 = 0; k0 < 4; ++k0)
#pragma unroll
      for (int n = 0; n < 8; ++n) {
        const u16x8 bv = *(const u16x8*)(wm + (n * 16 + la) * 128 + k0 * 32 + kg * 8);
        acc[n] = __builtin_amdgcn_mfma_f32_16x16x32_bf16(
            __builtin_bit_cast(bf16x8, af[k0]), __builtin_bit_cast(bf16x8, bv),
            acc[n], 0, 0, 0);
      }
  }
#pragma unroll
  for (int n = 0; n < 8; ++n) {
    const float bb = b1[n * 16 + la];
#pragma unroll
    for (int r = 0; r < 4; ++r) {
      const int lr = kg * 4 + r;
      *(u16*)(tileB + lr * 256 + (((n * 16 + la) * 2) ^ ((lr & 7) << 4))) =
          f2bf(acc[n][r] + bb);
    }
  }
  u16x8 hf[4];
#pragma unroll
  for (int k0 = 0; k0 < 4; ++k0) {
    const u16x8 sv = *(const u16x8*)(tileB + la * 256 + ((k0 * 64 + kg * 16) ^ swzA));
    u16x8 o;
#pragma unroll
    for (int j = 0; j < 8; ++j) {
      float v = bf2f(sv[j]) + bf2f(xn[k0][j]);
      o[j] = f2bf(v > 0.f ? v : 0.f);
    }
    hf[k0] = o;
  }

#pragma unroll
  for (int L = 0; L < 3; ++L) {
    const u16* wm = wt + (8 + L) * MW;
    const float* bias = L == 0 ? b2 : (L == 1 ? b3 : b4);
#pragma unroll
    for (int n = 0; n < 8; ++n) acc[n] = {0.f, 0.f, 0.f, 0.f};
#pragma unroll
    for (int k0 = 0; k0 < 4; ++k0)
#pragma unroll
      for (int n = 0; n < 8; ++n) {
        const u16x8 bv = *(const u16x8*)(wm + (n * 16 + la) * 128 + k0 * 32 + kg * 8);
        acc[n] = __builtin_amdgcn_mfma_f32_16x16x32_bf16(
            __builtin_bit_cast(bf16x8, hf[k0]), __builtin_bit_cast(bf16x8, bv),
            acc[n], 0, 0, 0);
      }
    if (L == 2) break;
#pragma unroll
    for (int n = 0; n < 8; ++n) {
      const float bb = bias[n * 16 + la];
#pragma unroll
      for (int r = 0; r < 4; ++r) {
        const int lr = kg * 4 + r;
        float v = acc[n][r] + bb;
        v = v > 0.f ? v : 0.f;
        *(u16*)(tileB + lr * 256 + (((n * 16 + la) * 2) ^ ((lr & 7) << 4))) = f2bf(v);
      }
    }
#pragma unroll
    for (int k0 = 0; k0 < 4; ++k0)
      hf[k0] = *(const u16x8*)(tileB + la * 256 + ((k0 * 64 + kg * 16) ^ swzA));
  }

  float vs[4] = {0, 0, 0, 0}, vq[4] = {0, 0, 0, 0};
#pragma unroll
  for (int n = 0; n < 8; ++n) {
    const float bb = b4[n * 16 + la];
#pragma unroll
    for (int r = 0; r < 4; ++r) {
      const float v = acc[n][r] + bb;
      acc[n][r] = v; vs[r] += v; vq[r] += v * v;
    }
  }
#pragma unroll
  for (int d = 1; d < 16; d <<= 1)
#pragma unroll
    for (int r = 0; r < 4; ++r) {
      vs[r] += __shfl_xor(vs[r], d, 64);
      vq[r] += __shfl_xor(vq[r], d, 64);
    }
#pragma unroll
  for (int r = 0; r < 4; ++r) {
    const int rowg = n0 + kg * 4 + r;
    if (rowg < N_NODES) {
      const float mean = vs[r] * (1.0f / 128.0f);
      const float var = vq[r] * (1.0f / 128.0f) - mean * mean;
      const float rstd = rsqrtf(var + 1e-5f);
      const size_t rbase = (size_t)rowg * H;
#pragma unroll
      for (int n = 0; n < 8; ++n) {
        const int col = n * 16 + la;
        const float ne = (acc[n][r] - mean) * rstd * g[col] + be[col];
        out1[rbase + col] = x[rbase + col] + ne;
      }
    }
  }
}

extern "C" void kernel_launch(void* const* d_in, const int* in_sizes, int n_in,
                              void* d_out, int out_size, void* d_ws, size_t ws_size,
                              hipStream_t stream) {
  const float* x   = (const float*)d_in[0];
  const float* ea  = (const float*)d_in[1];
  const int*   ei  = (const int*)d_in[2];
  const float* ew1 = (const float*)d_in[3];
  const float* eb1 = (const float*)d_in[4];
  const float* ew2 = (const float*)d_in[5];
  const float* eb2 = (const float*)d_in[6];
  const float* ew3 = (const float*)d_in[7];
  const float* eb3 = (const float*)d_in[8];
  const float* ew4 = (const float*)d_in[9];
  const float* eb4 = (const float*)d_in[10];
  const float* eg  = (const float*)d_in[11];
  const float* ebe = (const float*)d_in[12];
  const float* nw1 = (const float*)d_in[13];
  const float* nb1 = (const float*)d_in[14];
  const float* nw2 = (const float*)d_in[15];
  const float* nb2 = (const float*)d_in[16];
  const float* nw3 = (const float*)d_in[17];
  const float* nb3 = (const float*)d_in[18];
  const float* nw4 = (const float*)d_in[19];
  const float* nb4 = (const float*)d_in[20];
  const float* ng  = (const float*)d_in[21];
  const float* nbe = (const float*)d_in[22];

  char* ws = (char*)d_ws;
  u16* wt = (u16*)ws;
  u16* xa = (u16*)(ws + XA_OFF);
  u16* xb = (u16*)(ws + XB_OFF);
  u16* xn = (u16*)(ws + XN_OFF);
  float* agg = (float*)(ws + AGG_OFF);
  float* out1 = (float*)d_out;
  float* out2 = out1 + (size_t)N_NODES * H;

  hipMemsetAsync(agg, 0, (size_t)N_NODES * H * sizeof(float), stream);
  prep_weights<<<(11 * MW + 255) / 256, 256, 0, stream>>>(
      ew1, ew2, ew3, ew4, nw1, nw2, nw3, nw4, wt);
  precompute<<<(N_NODES + 63) / 64, 256, 0, stream>>>(x, wt, xa, xb, xn);
  edge_kernel<<<(N_EDGES + 127) / 128, 256, 0, stream>>>(
      ea, ei, wt, xa, xb, eb1, eb2, eb3, eb4, eg, ebe, out2, agg);
  node_kernel<<<(N_NODES + 63) / 64, 256, 0, stream>>>(
      x, agg, wt, xn, nb1, nb2, nb3, nb4, ng, nbe, out1);
}

// Round 4
// 950.174 us; speedup vs baseline: 1.2952x; 1.1400x over previous
//
#include <hip/hip_runtime.h>

#define N_NODES 50000
#define N_EDGES 600000
#define H 128

typedef __bf16 bf16x8 __attribute__((ext_vector_type(8)));
typedef float f32x4 __attribute__((ext_vector_type(4)));
typedef unsigned short u16;
typedef u16 u16x8 __attribute__((ext_vector_type(8)));

// d_ws layout (bytes):
//   wt: 11 matrices, each [128][128] bf16 transposed ([n][k], wt[n][k]=W[k][n])
//     0:E_W1a 1:E_W1b 2:E_W1c 3:E_W2 4:E_W3 5:E_W4 6:N_W1a 7:N_W1b 8:N_W2 9:N_W3 10:N_W4
#define MW 16384
#define WT_BYTES (11 * MW * 2)                     // 360448
#define XA_OFF WT_BYTES                            // 50000*128 bf16
#define XB_OFF (XA_OFF + N_NODES * H * 2)
#define XN_OFF (XB_OFF + N_NODES * H * 2)
#define AGG_OFF (XN_OFF + N_NODES * H * 2)         // f32

__device__ inline u16 f2bf(float f) { return __builtin_bit_cast(u16, (__bf16)f); }
__device__ inline float bf2f(u16 u) {
  unsigned v = (unsigned)u << 16;
  return __builtin_bit_cast(float, v);
}

__device__ inline u16x8 cvt8(const float* __restrict__ p) {
  const float4 f0 = ((const float4*)p)[0];
  const float4 f1 = ((const float4*)p)[1];
  u16x8 o;
  o[0] = f2bf(f0.x); o[1] = f2bf(f0.y); o[2] = f2bf(f0.z); o[3] = f2bf(f0.w);
  o[4] = f2bf(f1.x); o[5] = f2bf(f1.y); o[6] = f2bf(f1.z); o[7] = f2bf(f1.w);
  return o;
}

__global__ __launch_bounds__(256) void prep_weights(
    const float* __restrict__ ew1, const float* __restrict__ ew2,
    const float* __restrict__ ew3, const float* __restrict__ ew4,
    const float* __restrict__ nw1, const float* __restrict__ nw2,
    const float* __restrict__ nw3, const float* __restrict__ nw4,
    u16* __restrict__ wt)
{
  const int gid = blockIdx.x * 256 + threadIdx.x;
  if (gid >= 11 * MW) return;
  const int mat = gid >> 14, idx = gid & (MW - 1);
  const int n = idx >> 7, k = idx & 127;
  const float* src; int ro = 0;
  switch (mat) {
    case 0: src = ew1; ro = 0;   break;
    case 1: src = ew1; ro = 128; break;
    case 2: src = ew1; ro = 256; break;
    case 3: src = ew2; break;
    case 4: src = ew3; break;
    case 5: src = ew4; break;
    case 6: src = nw1; ro = 0;   break;
    case 7: src = nw1; ro = 128; break;
    case 8: src = nw2; break;
    case 9: src = nw3; break;
    default: src = nw4; break;
  }
  wt[gid] = f2bf(src[(ro + k) * H + n]);
}

// mfma_f32_16x16x32_bf16 layouts (HW-verified R1, absmax 0.031):
//   A: row = lane&15, k = (lane>>4)*8 + j
//   B: col = lane&15, k = (lane>>4)*8 + j
//   D: col = lane&15, row = (lane>>4)*4 + reg

// XA = x@E_W1a, XB = x@E_W1b, XN = x@N_W1a for all nodes, stored bf16
__global__ __launch_bounds__(256) void precompute(
    const float* __restrict__ x, const u16* __restrict__ wt,
    u16* __restrict__ xa, u16* __restrict__ xb, u16* __restrict__ xn)
{
  const int tid = threadIdx.x;
  const int lane = tid & 63, w = tid >> 6;
  const int n0 = blockIdx.x * 64 + w * 16;
  const int la = lane & 15, kg = lane >> 4;
  const int row = n0 + la < N_NODES ? n0 + la : N_NODES - 1;

  u16x8 af[4];
#pragma unroll
  for (int k0 = 0; k0 < 4; ++k0)
    af[k0] = cvt8(x + (size_t)row * H + k0 * 32 + kg * 8);

  const int mats[3] = {0, 1, 6};
  u16* outs[3] = {xa, xb, xn};
#pragma unroll
  for (int m = 0; m < 3; ++m) {
    const u16* wm = wt + mats[m] * MW;
    f32x4 acc[8];
#pragma unroll
    for (int n = 0; n < 8; ++n) acc[n] = {0.f, 0.f, 0.f, 0.f};
#pragma unroll
    for (int k0 = 0; k0 < 4; ++k0) {
      const bf16x8 a = __builtin_bit_cast(bf16x8, af[k0]);
#pragma unroll
      for (int n = 0; n < 8; ++n) {
        const u16x8 bv = *(const u16x8*)(wm + (n * 16 + la) * 128 + k0 * 32 + kg * 8);
        acc[n] = __builtin_amdgcn_mfma_f32_16x16x32_bf16(
            a, __builtin_bit_cast(bf16x8, bv), acc[n], 0, 0, 0);
      }
    }
    u16* out = outs[m];
#pragma unroll
    for (int r = 0; r < 4; ++r) {
      const int rg = n0 + kg * 4 + r;
      if (rg < N_NODES) {
#pragma unroll
        for (int n = 0; n < 8; ++n)
          out[(size_t)rg * H + n * 16 + la] = f2bf(acc[n][r]);
      }
    }
  }
}

__global__ __launch_bounds__(256, 4) void edge_kernel(
    const float* __restrict__ ea, const int* __restrict__ eidx,
    const u16* __restrict__ wt,
    const u16* __restrict__ xag, const u16* __restrict__ xbg,
    const float* __restrict__ b1, const float* __restrict__ b2,
    const float* __restrict__ b3, const float* __restrict__ b4,
    const float* __restrict__ g, const float* __restrict__ be,
    float* __restrict__ out2, float* __restrict__ agg)
{
  __shared__ u16 sH[4][4096];   // per-wave [32][128] bf16 tile (8 KiB), 32 KiB block
  const int tid = threadIdx.x;
  const int lane = tid & 63, w = tid >> 6;
  const int e0 = blockIdx.x * 128 + w * 32;   // this wave's 32 edges
  const int la = lane & 15, kg = lane >> 4;
  const int* __restrict__ snd = eidx;
  const int* __restrict__ rcv = eidx + N_EDGES;
  u16* tile = sH[w];
  char* tileB = (char*)tile;
  const int swzA = (la & 7) << 4;

  // rows this lane feeds as A-row (tile t: row e0+t*16+la)
  int rA[2];
  rA[0] = e0 + la;      if (rA[0] >= N_EDGES) rA[0] = N_EDGES - 1;
  rA[1] = e0 + 16 + la; if (rA[1] >= N_EDGES) rA[1] = N_EDGES - 1;

  // ea A-fragments (f32 -> bf16)
  u16x8 af[2][4];
#pragma unroll
  for (int t = 0; t < 2; ++t)
#pragma unroll
    for (int k0 = 0; k0 < 4; ++k0)
      af[t][k0] = cvt8(ea + (size_t)rA[t] * H + k0 * 32 + kg * 8);

  // ---- L1c: S = ea @ W1c (B shared across both tiles) ----
  f32x4 acc[2][8];
#pragma unroll
  for (int t = 0; t < 2; ++t)
#pragma unroll
    for (int n = 0; n < 8; ++n) acc[t][n] = {0.f, 0.f, 0.f, 0.f};
  {
    const u16* wm = wt + 2 * MW;
#pragma unroll
    for (int k0 = 0; k0 < 4; ++k0) {
#pragma unroll
      for (int n = 0; n < 8; ++n) {
        const u16x8 bv = *(const u16x8*)(wm + (n * 16 + la) * 128 + k0 * 32 + kg * 8);
        acc[0][n] = __builtin_amdgcn_mfma_f32_16x16x32_bf16(
            __builtin_bit_cast(bf16x8, af[0][k0]), __builtin_bit_cast(bf16x8, bv),
            acc[0][n], 0, 0, 0);
        acc[1][n] = __builtin_amdgcn_mfma_f32_16x16x32_bf16(
            __builtin_bit_cast(bf16x8, af[1][k0]), __builtin_bit_cast(bf16x8, bv),
            acc[1][n], 0, 0, 0);
      }
    }
  }

  // store S + b1 (no relu) to LDS tile; acc/af die here -> register headroom
#pragma unroll
  for (int t = 0; t < 2; ++t)
#pragma unroll
    for (int n = 0; n < 8; ++n) {
      const float bb = b1[n * 16 + la];
#pragma unroll
      for (int r = 0; r < 4; ++r) {
        const int lr = t * 16 + kg * 4 + r;
        *(u16*)(tileB + lr * 256 + (((n * 16 + la) * 2) ^ ((lr & 7) << 4))) =
            f2bf(acc[t][n][r] + bb);
      }
    }

  // gather XA[snd], XB[rcv] bf16 A-fragments NOW (after acc's live range)
  u16x8 xa[2][4], xb[2][4];
#pragma unroll
  for (int t = 0; t < 2; ++t) {
    const size_t sb = (size_t)snd[rA[t]] * H;
    const size_t rb = (size_t)rcv[rA[t]] * H;
#pragma unroll
    for (int k0 = 0; k0 < 4; ++k0) {
      xa[t][k0] = *(const u16x8*)(xag + sb + k0 * 32 + kg * 8);
      xb[t][k0] = *(const u16x8*)(xbg + rb + k0 * 32 + kg * 8);
    }
  }

  // h1 = relu(S + b1 + XA[snd] + XB[rcv]) in A-domain
  u16x8 hf[2][4];
#pragma unroll
  for (int t = 0; t < 2; ++t)
#pragma unroll
    for (int k0 = 0; k0 < 4; ++k0) {
      const u16x8 sv = *(const u16x8*)(tileB + (t * 16 + la) * 256 +
                                       ((k0 * 64 + kg * 16) ^ swzA));
      u16x8 o;
#pragma unroll
      for (int j = 0; j < 8; ++j) {
        float v = bf2f(sv[j]) + bf2f(xa[t][k0][j]) + bf2f(xb[t][k0][j]);
        o[j] = f2bf(v > 0.f ? v : 0.f);
      }
      hf[t][k0] = o;
    }

  // ---- layers 2..4 ----
#pragma unroll
  for (int L = 0; L < 3; ++L) {
    const u16* wm = wt + (3 + L) * MW;
    const float* bias = L == 0 ? b2 : (L == 1 ? b3 : b4);
#pragma unroll
    for (int t = 0; t < 2; ++t)
#pragma unroll
      for (int n = 0; n < 8; ++n) acc[t][n] = {0.f, 0.f, 0.f, 0.f};
#pragma unroll
    for (int k0 = 0; k0 < 4; ++k0) {
#pragma unroll
      for (int n = 0; n < 8; ++n) {
        const u16x8 bv = *(const u16x8*)(wm + (n * 16 + la) * 128 + k0 * 32 + kg * 8);
        acc[0][n] = __builtin_amdgcn_mfma_f32_16x16x32_bf16(
            __builtin_bit_cast(bf16x8, hf[0][k0]), __builtin_bit_cast(bf16x8, bv),
            acc[0][n], 0, 0, 0);
        acc[1][n] = __builtin_amdgcn_mfma_f32_16x16x32_bf16(
            __builtin_bit_cast(bf16x8, hf[1][k0]), __builtin_bit_cast(bf16x8, bv),
            acc[1][n], 0, 0, 0);
      }
    }
    if (L == 2) break;   // L4 result stays in acc for LN
    // store relu(acc + bias) and reload A-fragments
#pragma unroll
    for (int t = 0; t < 2; ++t)
#pragma unroll
      for (int n = 0; n < 8; ++n) {
        const float bb = bias[n * 16 + la];
#pragma unroll
        for (int r = 0; r < 4; ++r) {
          const int lr = t * 16 + kg * 4 + r;
          float v = acc[t][n][r] + bb;
          v = v > 0.f ? v : 0.f;
          *(u16*)(tileB + lr * 256 + (((n * 16 + la) * 2) ^ ((lr & 7) << 4))) = f2bf(v);
        }
      }
#pragma unroll
    for (int t = 0; t < 2; ++t)
#pragma unroll
      for (int k0 = 0; k0 < 4; ++k0)
        hf[t][k0] = *(const u16x8*)(tileB + (t * 16 + la) * 256 +
                                    ((k0 * 64 + kg * 16) ^ swzA));
  }

  // ---- bias4 + LayerNorm + residual + scatter-add ----
  float vs[2][4], vq[2][4];
#pragma unroll
  for (int t = 0; t < 2; ++t)
#pragma unroll
    for (int r = 0; r < 4; ++r) { vs[t][r] = 0.f; vq[t][r] = 0.f; }
#pragma unroll
  for (int t = 0; t < 2; ++t)
#pragma unroll
    for (int n = 0; n < 8; ++n) {
      const float bb = b4[n * 16 + la];
#pragma unroll
      for (int r = 0; r < 4; ++r) {
        const float v = acc[t][n][r] + bb;
        acc[t][n][r] = v;
        vs[t][r] += v; vq[t][r] += v * v;
      }
    }
#pragma unroll
  for (int d = 1; d < 16; d <<= 1)
#pragma unroll
    for (int t = 0; t < 2; ++t)
#pragma unroll
      for (int r = 0; r < 4; ++r) {
        vs[t][r] += __shfl_xor(vs[t][r], d, 64);
        vq[t][r] += __shfl_xor(vq[t][r], d, 64);
      }
#pragma unroll
  for (int t = 0; t < 2; ++t)
#pragma unroll
    for (int r = 0; r < 4; ++r) {
      const int rowg = e0 + t * 16 + kg * 4 + r;
      if (rowg < N_EDGES) {
        const float mean = vs[t][r] * (1.0f / 128.0f);
        const float var = vq[t][r] * (1.0f / 128.0f) - mean * mean;
        const float rstd = rsqrtf(var + 1e-5f);
        const int rv = rcv[rowg];
        const size_t rbase = (size_t)rowg * H;
        const size_t abase = (size_t)rv * H;
#pragma unroll
        for (int n = 0; n < 8; ++n) {
          const int col = n * 16 + la;
          const float ne = (acc[t][n][r] - mean) * rstd * g[col] + be[col];
          out2[rbase + col] = ea[rbase + col] + ne;
          atomicAdd(agg + abase + col, ne);
        }
      }
    }
}

__global__ __launch_bounds__(256, 4) void node_kernel(
    const float* __restrict__ x, const float* __restrict__ agg,
    const u16* __restrict__ wt, const u16* __restrict__ xng,
    const float* __restrict__ b1, const float* __restrict__ b2,
    const float* __restrict__ b3, const float* __restrict__ b4,
    const float* __restrict__ g, const float* __restrict__ be,
    float* __restrict__ out1)
{
  __shared__ u16 sH[4][2048];
  const int tid = threadIdx.x;
  const int lane = tid & 63, w = tid >> 6;
  const int n0 = blockIdx.x * 64 + w * 16;
  const int la = lane & 15, kg = lane >> 4;
  u16* tile = sH[w];
  char* tileB = (char*)tile;
  const int swzA = (la & 7) << 4;

  const int row = n0 + la < N_NODES ? n0 + la : N_NODES - 1;

  u16x8 af[4];
#pragma unroll
  for (int k0 = 0; k0 < 4; ++k0)
    af[k0] = cvt8(agg + (size_t)row * H + k0 * 32 + kg * 8);

  // L1b: S = agg @ N_W1b
  f32x4 acc[8];
#pragma unroll
  for (int n = 0; n < 8; ++n) acc[n] = {0.f, 0.f, 0.f, 0.f};
  {
    const u16* wm = wt + 7 * MW;
#pragma unroll
    for (int k0 = 0; k0 < 4; ++k0)
#pragma unroll
      for (int n = 0; n < 8; ++n) {
        const u16x8 bv = *(const u16x8*)(wm + (n * 16 + la) * 128 + k0 * 32 + kg * 8);
        acc[n] = __builtin_amdgcn_mfma_f32_16x16x32_bf16(
            __builtin_bit_cast(bf16x8, af[k0]), __builtin_bit_cast(bf16x8, bv),
            acc[n], 0, 0, 0);
      }
  }
#pragma unroll
  for (int n = 0; n < 8; ++n) {
    const float bb = b1[n * 16 + la];
#pragma unroll
    for (int r = 0; r < 4; ++r) {
      const int lr = kg * 4 + r;
      *(u16*)(tileB + lr * 256 + (((n * 16 + la) * 2) ^ ((lr & 7) << 4))) =
          f2bf(acc[n][r] + bb);
    }
  }
  u16x8 xn[4];
#pragma unroll
  for (int k0 = 0; k0 < 4; ++k0)
    xn[k0] = *(const u16x8*)(xng + (size_t)row * H + k0 * 32 + kg * 8);
  u16x8 hf[4];
#pragma unroll
  for (int k0 = 0; k0 < 4; ++k0) {
    const u16x8 sv = *(const u16x8*)(tileB + la * 256 + ((k0 * 64 + kg * 16) ^ swzA));
    u16x8 o;
#pragma unroll
    for (int j = 0; j < 8; ++j) {
      float v = bf2f(sv[j]) + bf2f(xn[k0][j]);
      o[j] = f2bf(v > 0.f ? v : 0.f);
    }
    hf[k0] = o;
  }

#pragma unroll
  for (int L = 0; L < 3; ++L) {
    const u16* wm = wt + (8 + L) * MW;
    const float* bias = L == 0 ? b2 : (L == 1 ? b3 : b4);
#pragma unroll
    for (int n = 0; n < 8; ++n) acc[n] = {0.f, 0.f, 0.f, 0.f};
#pragma unroll
    for (int k0 = 0; k0 < 4; ++k0)
#pragma unroll
      for (int n = 0; n < 8; ++n) {
        const u16x8 bv = *(const u16x8*)(wm + (n * 16 + la) * 128 + k0 * 32 + kg * 8);
        acc[n] = __builtin_amdgcn_mfma_f32_16x16x32_bf16(
            __builtin_bit_cast(bf16x8, hf[k0]), __builtin_bit_cast(bf16x8, bv),
            acc[n], 0, 0, 0);
      }
    if (L == 2) break;
#pragma unroll
    for (int n = 0; n < 8; ++n) {
      const float bb = bias[n * 16 + la];
#pragma unroll
      for (int r = 0; r < 4; ++r) {
        const int lr = kg * 4 + r;
        float v = acc[n][r] + bb;
        v = v > 0.f ? v : 0.f;
        *(u16*)(tileB + lr * 256 + (((n * 16 + la) * 2) ^ ((lr & 7) << 4))) = f2bf(v);
      }
    }
#pragma unroll
    for (int k0 = 0; k0 < 4; ++k0)
      hf[k0] = *(const u16x8*)(tileB + la * 256 + ((k0 * 64 + kg * 16) ^ swzA));
  }

  float vs[4] = {0, 0, 0, 0}, vq[4] = {0, 0, 0, 0};
#pragma unroll
  for (int n = 0; n < 8; ++n) {
    const float bb = b4[n * 16 + la];
#pragma unroll
    for (int r = 0; r < 4; ++r) {
      const float v = acc[n][r] + bb;
      acc[n][r] = v; vs[r] += v; vq[r] += v * v;
    }
  }
#pragma unroll
  for (int d = 1; d < 16; d <<= 1)
#pragma unroll
    for (int r = 0; r < 4; ++r) {
      vs[r] += __shfl_xor(vs[r], d, 64);
      vq[r] += __shfl_xor(vq[r], d, 64);
    }
#pragma unroll
  for (int r = 0; r < 4; ++r) {
    const int rowg = n0 + kg * 4 + r;
    if (rowg < N_NODES) {
      const float mean = vs[r] * (1.0f / 128.0f);
      const float var = vq[r] * (1.0f / 128.0f) - mean * mean;
      const float rstd = rsqrtf(var + 1e-5f);
      const size_t rbase = (size_t)rowg * H;
#pragma unroll
      for (int n = 0; n < 8; ++n) {
        const int col = n * 16 + la;
        const float ne = (acc[n][r] - mean) * rstd * g[col] + be[col];
        out1[rbase + col] = x[rbase + col] + ne;
      }
    }
  }
}

extern "C" void kernel_launch(void* const* d_in, const int* in_sizes, int n_in,
                              void* d_out, int out_size, void* d_ws, size_t ws_size,
                              hipStream_t stream) {
  const float* x   = (const float*)d_in[0];
  const float* ea  = (const float*)d_in[1];
  const int*   ei  = (const int*)d_in[2];
  const float* ew1 = (const float*)d_in[3];
  const float* eb1 = (const float*)d_in[4];
  const float* ew2 = (const float*)d_in[5];
  const float* eb2 = (const float*)d_in[6];
  const float* ew3 = (const float*)d_in[7];
  const float* eb3 = (const float*)d_in[8];
  const float* ew4 = (const float*)d_in[9];
  const float* eb4 = (const float*)d_in[10];
  const float* eg  = (const float*)d_in[11];
  const float* ebe = (const float*)d_in[12];
  const float* nw1 = (const float*)d_in[13];
  const float* nb1 = (const float*)d_in[14];
  const float* nw2 = (const float*)d_in[15];
  const float* nb2 = (const float*)d_in[16];
  const float* nw3 = (const float*)d_in[17];
  const float* nb3 = (const float*)d_in[18];
  const float* nw4 = (const float*)d_in[19];
  const float* nb4 = (const float*)d_in[20];
  const float* ng  = (const float*)d_in[21];
  const float* nbe = (const float*)d_in[22];

  char* ws = (char*)d_ws;
  u16* wt = (u16*)ws;
  u16* xa = (u16*)(ws + XA_OFF);
  u16* xb = (u16*)(ws + XB_OFF);
  u16* xn = (u16*)(ws + XN_OFF);
  float* agg = (float*)(ws + AGG_OFF);
  float* out1 = (float*)d_out;
  float* out2 = out1 + (size_t)N_NODES * H;

  hipMemsetAsync(agg, 0, (size_t)N_NODES * H * sizeof(float), stream);
  prep_weights<<<(11 * MW + 255) / 256, 256, 0, stream>>>(
      ew1, ew2, ew3, ew4, nw1, nw2, nw3, nw4, wt);
  precompute<<<(N_NODES + 63) / 64, 256, 0, stream>>>(x, wt, xa, xb, xn);
  edge_kernel<<<(N_EDGES + 127) / 128, 256, 0, stream>>>(
      ea, ei, wt, xa, xb, eb1, eb2, eb3, eb4, eg, ebe, out2, agg);
  node_kernel<<<(N_NODES + 63) / 64, 256, 0, stream>>>(
      x, agg, wt, xn, nb1, nb2, nb3, nb4, ng, nbe, out1);
}